// Round 2
// baseline (389.739 us; speedup 1.0000x reference)
//
#include <hip/hip_runtime.h>
#include <hip/hip_bf16.h>

#define NQ   8
#define HID  768
#define BATCH 8192
#define TPB  256
#define NBLK (BATCH / 16)            // 512 blocks, 16 samples each

typedef __attribute__((ext_vector_type(8))) short sv8;
typedef __attribute__((ext_vector_type(4))) float fv4;

// ---------- dtype-generic load/store ----------
template<int BF> __device__ __forceinline__ float LDV(const void* p, int i) {
    if constexpr (BF) return __bfloat162float(((const __hip_bfloat16*)p)[i]);
    else return ((const float*)p)[i];
}

__device__ __forceinline__ unsigned short f2bf(float x) {
    unsigned int u = __float_as_uint(x);
    unsigned int r = (u + 0x7fffu + ((u >> 16) & 1u)) >> 16;   // RNE
    return (unsigned short)r;
}

// ---------- circuit closed form (verified round 1): z pre-tanh (b_in added) ----------
__device__ __forceinline__ void circuit(const float* zz, const float* qc, float* meas) {
    float sc[NQ], cc[NQ];
    #pragma unroll
    for (int j = 0; j < NQ; ++j) {
        float t_ = tanhf(zz[j]);          // theta = pi * t_
        sc[j] = sinpif(t_);
        cc[j] = cospif(t_);
    }
    float PA = 1.f, PB = 1.f, PFr = 1.f, PFi = 0.f;
    #pragma unroll
    for (int j = 1; j < NQ; ++j) {
        float DA = qc[4*j], DB = qc[4*j+1], Kr = qc[4*j+2], Ki = qc[4*j+3];
        float ca = 0.5f*(DA+DB), da = 0.5f*(DA-DB);
        float u = da * cc[j];
        float v = fmaf(Kr, sc[j], ca);
        meas[j] = fmaf(cc[0], u, v);
        PA *= (v + u); PB *= (v - u);
        float fr = Kr, fi = cc[j]*Ki;
        float nr = PFr*fr - PFi*fi;
        float ni = PFr*fi + PFi*fr;
        PFr = nr; PFi = ni;
    }
    float DA0 = qc[0], DB0 = qc[1], Kr0 = qc[2], Ki0 = qc[3];
    meas[0] = 0.5f*(1.f+cc[0])*DA0*PA + 0.5f*(1.f-cc[0])*DB0*PB
            + sc[0]*(Kr0*PFr - Ki0*PFi);
}

// ws layout: int flag at byte 0; float qc[32] at byte 16
__global__ void setup_kernel(const void* hidden, const void* wry, const void* wrz, void* ws) {
    __shared__ int votes;
    __shared__ int sFlag;
    int tid = threadIdx.x;
    if (tid == 0) votes = 0;
    __syncthreads();
    const unsigned int* hw = (const unsigned int*)hidden;
    int cnt = 0;
    #pragma unroll
    for (int k = 0; k < 16; ++k) {
        unsigned int w = hw[tid * 16 + k];
        unsigned int lo = w & 0xffffu;
        unsigned int e = (lo >> 7) & 0xffu;
        if (lo == 0u || (e >= 100u && e <= 133u)) cnt++;
    }
    atomicAdd(&votes, cnt);
    __syncthreads();
    if (tid == 0) {
        sFlag = (votes * 2 > TPB * 16) ? 1 : 0;
        *(int*)ws = sFlag;
    }
    __syncthreads();
    const int flag = sFlag;
    if (tid < NQ) {
        float ry0, ry1, rz0, rz1;
        if (flag) {
            ry0 = LDV<1>(wry, tid);  ry1 = LDV<1>(wry, NQ + tid);
            rz0 = LDV<1>(wrz, tid);  rz1 = LDV<1>(wrz, NQ + tid);
        } else {
            ry0 = LDV<0>(wry, tid);  ry1 = LDV<0>(wry, NQ + tid);
            rz0 = LDV<0>(wrz, tid);  rz1 = LDV<0>(wrz, NQ + tid);
        }
        float cA = cosf(0.5f*ry0), sA = sinf(0.5f*ry0);
        float cB = cosf(0.5f*ry1), sB = sinf(0.5f*ry1);
        float p0c = cosf(0.5f*rz0), p0s = sinf(0.5f*rz0);
        float p1c = cosf(0.5f*rz1), p1s = sinf(0.5f*rz1);
        float g00r =  cA*p0c, g00i = -cA*p0s;
        float g01r = -sA*p0c, g01i =  sA*p0s;
        float g10r =  sA*p0c, g10i =  sA*p0s;
        float g11r =  cA*p0c, g11i =  cA*p0s;
        float h00r = cB*g00r - sB*g10r, h00i = cB*g00i - sB*g10i;
        float h01r = cB*g01r - sB*g11r, h01i = cB*g01i - sB*g11i;
        float h10r = sB*g00r + cB*g10r, h10i = sB*g00i + cB*g10i;
        float h11r = sB*g01r + cB*g11r, h11i = sB*g01i + cB*g11i;
        float f00r = h00r*p1c + h00i*p1s, f00i = h00i*p1c - h00r*p1s;
        float f01r = h01r*p1c + h01i*p1s, f01i = h01i*p1c - h01r*p1s;
        float f10r = h10r*p1c - h10i*p1s, f10i = h10i*p1c + h10r*p1s;
        float f11r = h11r*p1c - h11i*p1s, f11i = h11i*p1c + h11r*p1s;
        float DA = f00r*f00r + f00i*f00i - (f10r*f10r + f10i*f10i);
        float DB = f01r*f01r + f01i*f01i - (f11r*f11r + f11i*f11i);
        float Kr = (f00r*f01r + f00i*f01i) - (f10r*f11r + f10i*f11i);
        float Ki = (f00i*f01r - f00r*f01i) - (f10i*f11r - f10r*f11i);
        float* qc = (float*)((char*)ws + 16);
        qc[tid*4+0] = DA; qc[tid*4+1] = DB; qc[tid*4+2] = Kr; qc[tid*4+3] = Ki;
    }
}

__global__ __launch_bounds__(TPB) void main_kernel(
    const void* hidden_, const void* W_in_, const void* b_in_,
    const void* W_out_, const void* b_out_, const void* gamma_, const void* beta_,
    void* out_, const void* ws_)
{
    __shared__ float zp[4][16][17];    // padded: conflict-free gather
    __shared__ float lnp[4][16][2];
    __shared__ float sQC[32];
    __shared__ float sBin[8];

    const int flag = *(const int*)ws_;
    const float* qc = (const float*)((const char*)ws_ + 16);
    const int tid = threadIdx.x;

    if (flag) {
        // ================= bf16 MFMA path =================
        const __hip_bfloat16* H  = (const __hip_bfloat16*)hidden_;
        const __hip_bfloat16* WI = (const __hip_bfloat16*)W_in_;
        const __hip_bfloat16* WO = (const __hip_bfloat16*)W_out_;
        __hip_bfloat16*       O  = (__hip_bfloat16*)out_;

        const int lane = tid & 63;
        const int w    = tid >> 6;         // wave 0..3  (K-split / N-split)
        const int n16  = lane & 15;
        const int quad = lane >> 4;

        if (tid < 32) sQC[tid] = qc[tid];
        if (tid < 8)  sBin[tid] = LDV<1>(b_in_, tid);

        // ---- phase A: z(16x8) = hidden_tile(16x768) @ W_in^T, K split 4 ways ----
        const sv8 bz = {0,0,0,0,0,0,0,0};
        fv4 acc = {0.f,0.f,0.f,0.f};
        const int rowA = blockIdx.x * 16 + n16;
        const sv8* Arow = (const sv8*)(H + (size_t)rowA * HID);
        #pragma unroll
        for (int t = 0; t < 6; ++t) {
            int k  = w*192 + t*32 + quad*8;        // element offset in K
            sv8 av = Arow[k >> 3];
            sv8 bv = bz;
            if (n16 < 8) bv = *(const sv8*)(WI + (size_t)n16 * HID + k);
            acc = __builtin_amdgcn_mfma_f32_16x16x32_bf16(av, bv, acc, 0, 0, 0);
        }
        #pragma unroll
        for (int r = 0; r < 4; ++r) zp[w][quad*4 + r][n16] = acc[r];
        __syncthreads();

        // ---- circuit: lane computes sample s = n16 (x4 redundant per wave) ----
        float z[8];
        #pragma unroll
        for (int q = 0; q < 8; ++q) {
            float v = zp[0][n16][q] + zp[1][n16][q] + zp[2][n16][q] + zp[3][n16][q];
            z[q] = v + sBin[q];
        }
        float meas[8];
        circuit(z, sQC, meas);

        // ---- phase C A-frag: quad0 carries meas (K=8, rest zero-padded) ----
        union { sv8 v; unsigned short u[8]; } am;
        am.v = bz;
        if (quad == 0) {
            #pragma unroll
            for (int j = 0; j < 8; ++j) am.u[j] = f2bf(meas[j]);
        }

        // ---- phase C: y(16 x 192-per-wave) = meas @ W_out^T + b_out ----
        float y[12][4];
        float s1[4] = {0,0,0,0}, s2[4] = {0,0,0,0};
        const fv4 zc = {0.f,0.f,0.f,0.f};
        #pragma unroll
        for (int i = 0; i < 12; ++i) {
            int nt = w*12 + i;
            int cb = nt*16 + n16;                  // global output column
            sv8 bv = bz;
            if (quad == 0) bv = *(const sv8*)(WO + (size_t)cb * 8);
            fv4 yy = __builtin_amdgcn_mfma_f32_16x16x32_bf16(am.v, bv, zc, 0, 0, 0);
            float bias = LDV<1>(b_out_, cb);
            #pragma unroll
            for (int r = 0; r < 4; ++r) {
                float v = yy[r] + bias;
                y[i][r] = v;
                s1[r] += v;
                s2[r] = fmaf(v, v, s2[r]);
            }
        }
        // reduce LN partials across the 16 lanes of each quad
        #pragma unroll
        for (int d = 1; d < 16; d <<= 1) {
            #pragma unroll
            for (int r = 0; r < 4; ++r) {
                s1[r] += __shfl_xor(s1[r], d, 64);
                s2[r] += __shfl_xor(s2[r], d, 64);
            }
        }
        if (n16 == 0) {
            #pragma unroll
            for (int r = 0; r < 4; ++r) {
                lnp[w][quad*4 + r][0] = s1[r];
                lnp[w][quad*4 + r][1] = s2[r];
            }
        }
        __syncthreads();
        float mean[4], rstd[4];
        #pragma unroll
        for (int r = 0; r < 4; ++r) {
            int row = quad*4 + r;
            float a = lnp[0][row][0] + lnp[1][row][0] + lnp[2][row][0] + lnp[3][row][0];
            float b = lnp[0][row][1] + lnp[1][row][1] + lnp[2][row][1] + lnp[3][row][1];
            float m = a * (1.f/HID);
            float var = b * (1.f/HID) - m*m;
            mean[r] = m;
            rstd[r] = rsqrtf(var + 1e-5f);
        }
        // ---- normalize + packed bf16x2 stores ----
        #pragma unroll
        for (int i = 0; i < 12; ++i) {
            int nt = w*12 + i;
            int cb = nt*16 + n16;
            float g  = LDV<1>(gamma_, cb);
            float be = LDV<1>(beta_,  cb);
            int colp = nt*16 + (n16 & ~1);
            #pragma unroll
            for (int r = 0; r < 4; ++r) {
                float v = (y[i][r] - mean[r]) * rstd[r] * g + be;
                float o = __shfl_xor(v, 1, 64);
                unsigned short hv = f2bf(v), ho = f2bf(o);
                unsigned int dw = (lane & 1) ? ((unsigned int)ho | ((unsigned int)hv << 16))
                                             : ((unsigned int)hv | ((unsigned int)ho << 16));
                if ((lane & 1) == (r & 1)) {
                    int row = blockIdx.x * 16 + quad*4 + r;
                    *(unsigned int*)(O + (size_t)row * HID + colp) = dw;
                }
            }
        }
    } else {
        // ================= fp32 fallback (correctness path) =================
        int b = blockIdx.x * TPB + tid;          // 131072 threads, first 8192 active
        if (b >= BATCH) return;
        const float* H  = (const float*)hidden_;
        const float* WI = (const float*)W_in_;
        const float* WO = (const float*)W_out_;
        float* O = (float*)out_;
        float z[8];
        #pragma unroll
        for (int j = 0; j < 8; ++j) z[j] = LDV<0>(b_in_, j);
        for (int c = 0; c < HID; ++c) {
            float h = H[(size_t)b * HID + c];
            #pragma unroll
            for (int j = 0; j < 8; ++j) z[j] = fmaf(h, WI[j*HID + c], z[j]);
        }
        float meas[8];
        circuit(z, qc, meas);
        float s1 = 0.f, s2 = 0.f;
        for (int h = 0; h < HID; ++h) {
            float v = LDV<0>(b_out_, h);
            #pragma unroll
            for (int j = 0; j < 8; ++j) v = fmaf(meas[j], WO[h*8 + j], v);
            s1 += v; s2 = fmaf(v, v, s2);
        }
        float m = s1 * (1.f/HID);
        float var = s2 * (1.f/HID) - m*m;
        float rs = rsqrtf(var + 1e-5f);
        for (int h = 0; h < HID; ++h) {
            float v = LDV<0>(b_out_, h);
            #pragma unroll
            for (int j = 0; j < 8; ++j) v = fmaf(meas[j], WO[h*8 + j], v);
            O[(size_t)b * HID + h] = (v - m) * rs * LDV<0>(gamma_, h) + LDV<0>(beta_, h);
        }
    }
}

extern "C" void kernel_launch(void* const* d_in, const int* in_sizes, int n_in,
                              void* d_out, int out_size, void* d_ws, size_t ws_size,
                              hipStream_t stream) {
    const void* hidden = d_in[0];
    const void* W_in   = d_in[1];
    const void* b_in   = d_in[2];
    const void* W_out  = d_in[3];
    const void* b_out  = d_in[4];
    const void* wry    = d_in[5];
    const void* wrz    = d_in[6];
    const void* gamma  = d_in[7];
    const void* beta   = d_in[8];
    setup_kernel<<<1, TPB, 0, stream>>>(hidden, wry, wrz, d_ws);
    main_kernel<<<NBLK, TPB, 0, stream>>>(hidden, W_in, b_in, W_out, b_out,
                                          gamma, beta, d_out, d_ws);
}

// Round 3
// 358.834 us; speedup vs baseline: 1.0861x; 1.0861x over previous
//
#include <hip/hip_runtime.h>
#include <hip/hip_bf16.h>

#define HID   768
#define BATCH 8192
#define NBLK  (BATCH / 4)        // 2048 blocks x 64 threads, 4 samples/block
#define PI_F  3.14159265358979323846f

typedef unsigned int uint;

__device__ __forceinline__ float bflo(uint u) { return __uint_as_float(u << 16); }
__device__ __forceinline__ float bfhi(uint u) { return __uint_as_float(u & 0xffff0000u); }
__device__ __forceinline__ uint  f2bf(float x) {
    uint u = __float_as_uint(x);
    return (u + 0x7fffu + ((u >> 16) & 1u)) >> 16;     // RNE
}
__device__ __forceinline__ float tanh_fast(float z) {
    float e = __expf(z + z);                            // e^{2z}
    return fmaf(-2.f, __builtin_amdgcn_rcpf(e + 1.f), 1.f);
}

// generic circuit (fallback path; math verified rounds 1-2)
__device__ void circuit_qc(const float* zz, const float* qc, float* meas) {
    float sc[8], cc[8];
    #pragma unroll
    for (int j = 0; j < 8; ++j) {
        float t_ = tanhf(zz[j]);
        sc[j] = sinpif(t_);
        cc[j] = cospif(t_);
    }
    float PA = 1.f, PB = 1.f, Fr = 1.f, Fi = 0.f;
    #pragma unroll
    for (int j = 1; j < 8; ++j) {
        float DA = qc[4*j], DB = qc[4*j+1], Kr = qc[4*j+2], Ki = qc[4*j+3];
        float ca = 0.5f*(DA+DB), da = 0.5f*(DA-DB);
        float u = da * cc[j];
        float v = fmaf(Kr, sc[j], ca);
        meas[j] = fmaf(cc[0], u, v);
        PA *= (v + u); PB *= (v - u);
        float fi = cc[j]*Ki;
        float nr = Fr*Kr - Fi*fi;
        Fi = Fr*fi + Fi*Kr; Fr = nr;
    }
    meas[0] = 0.5f*(1.f+cc[0])*qc[0]*PA + 0.5f*(1.f-cc[0])*qc[1]*PB
            + sc[0]*(qc[2]*Fr - qc[3]*Fi);
}

__global__ __launch_bounds__(64) void fused_kernel(
    const void* H_, const void* WI_, const void* bin_, const void* WO_,
    const void* bout_, const void* wry_, const void* wrz_,
    const void* gam_, const void* bet_, void* out_)
{
    const int lane = threadIdx.x;
    const uint* Hd = (const uint*)H_;

    // ---- per-block dtype sniff (1 dword/lane of own tile, within bf16 extent) ----
    uint probe = Hd[(size_t)blockIdx.x * 1536 + lane];
    uint l0 = probe & 0xffffu, h0 = probe >> 16;
    uint e0 = (l0 >> 7) & 0xffu, e1 = (h0 >> 7) & 0xffu;
    bool okk = (l0 == 0u || (e0 >= 100u && e0 <= 133u)) &&
               (h0 == 0u || (e1 >= 100u && e1 <= 133u));
    unsigned long long bm = __ballot(okk);

    if (__popcll(bm) >= 32) {
        // ================= bf16 fast path =================
        const uint* WId = (const uint*)WI_;     // 8 rows x 384 dwords
        const uint* WOd = (const uint*)WO_;     // 768 rows x 4 dwords
        const uint* BOd = (const uint*)bout_;
        const uint* GAd = (const uint*)gam_;
        const uint* BEd = (const uint*)bet_;
        const __hip_bfloat16* BIN = (const __hip_bfloat16*)bin_;
        const __hip_bfloat16* WRY = (const __hip_bfloat16*)wry_;
        const __hip_bfloat16* WRZ = (const __hip_bfloat16*)wrz_;
        uint* Od = (uint*)out_;

        // ---- per-lane qubit constants (lane&7 owns qubit), broadcast by shfl ----
        float ca_, da_, kr_, ki_;
        {
            int q = lane & 7;
            float ry0 = __bfloat162float(WRY[q]);
            float ry1 = __bfloat162float(WRY[8 + q]);
            float rz0 = __bfloat162float(WRZ[q]);
            float rz1 = __bfloat162float(WRZ[8 + q]);
            float cA = cosf(0.5f*ry0), sA = sinf(0.5f*ry0);
            float cB = cosf(0.5f*ry1), sB = sinf(0.5f*ry1);
            float p0c = cosf(0.5f*rz0), p0s = sinf(0.5f*rz0);
            float p1c = cosf(0.5f*rz1), p1s = sinf(0.5f*rz1);
            float g00r =  cA*p0c, g00i = -cA*p0s;
            float g01r = -sA*p0c, g01i =  sA*p0s;
            float g10r =  sA*p0c, g10i =  sA*p0s;
            float g11r =  cA*p0c, g11i =  cA*p0s;
            float h00r = cB*g00r - sB*g10r, h00i = cB*g00i - sB*g10i;
            float h01r = cB*g01r - sB*g11r, h01i = cB*g01i - sB*g11i;
            float h10r = sB*g00r + cB*g10r, h10i = sB*g00i + cB*g10i;
            float h11r = sB*g01r + cB*g11r, h11i = sB*g01i + cB*g11i;
            float f00r = h00r*p1c + h00i*p1s, f00i = h00i*p1c - h00r*p1s;
            float f01r = h01r*p1c + h01i*p1s, f01i = h01i*p1c - h01r*p1s;
            float f10r = h10r*p1c - h10i*p1s, f10i = h10i*p1c + h10r*p1s;
            float f11r = h11r*p1c - h11i*p1s, f11i = h11i*p1c + h11r*p1s;
            float DA = f00r*f00r + f00i*f00i - (f10r*f10r + f10i*f10i);
            float DB = f01r*f01r + f01i*f01i - (f11r*f11r + f11i*f11i);
            float Kr = (f00r*f01r + f00i*f01i) - (f10r*f11r + f10i*f11i);
            float Ki = (f00i*f01r - f00r*f01i) - (f10i*f11r - f10r*f11i);
            ca_ = 0.5f*(DA + DB); da_ = 0.5f*(DA - DB); kr_ = Kr; ki_ = Ki;
        }
        // ---- persistent small params ----
        uint bod[6], gad[6], bed[6];
        #pragma unroll
        for (int d = 0; d < 6; ++d) {
            bod[d] = BOd[lane*6 + d];
            gad[d] = GAd[lane*6 + d];
            bed[d] = BEd[lane*6 + d];
        }
        float bin0[8];
        #pragma unroll
        for (int j = 0; j < 8; ++j) bin0[j] = __bfloat162float(BIN[j]);

        for (int p = 0; p < 2; ++p) {           // 2 pairs of samples
            const size_t r0 = (size_t)blockIdx.x * 4 + p*2;
            const uint* h0p = Hd + r0*384 + lane*6;
            uint ha[6], hb[6];
            { uint2 a = *(const uint2*)(h0p),     b = *(const uint2*)(h0p+2),   c = *(const uint2*)(h0p+4);
              ha[0]=a.x; ha[1]=a.y; ha[2]=b.x; ha[3]=b.y; ha[4]=c.x; ha[5]=c.y; }
            { const uint* h1p = h0p + 384;
              uint2 a = *(const uint2*)(h1p),     b = *(const uint2*)(h1p+2),   c = *(const uint2*)(h1p+4);
              hb[0]=a.x; hb[1]=a.y; hb[2]=b.x; hb[3]=b.y; hb[4]=c.x; hb[5]=c.y; }

            // W_in tile (L1/L2-hot) into registers for this pair
            uint wiL[48];
            #pragma unroll
            for (int j = 0; j < 8; ++j) {
                const uint2* wp = (const uint2*)(WId + j*384 + lane*6);
                uint2 a = wp[0], b = wp[1], c = wp[2];
                wiL[j*6+0]=a.x; wiL[j*6+1]=a.y; wiL[j*6+2]=b.x;
                wiL[j*6+3]=b.y; wiL[j*6+4]=c.x; wiL[j*6+5]=c.y;
            }
            float za[8] = {0,0,0,0,0,0,0,0}, zb[8] = {0,0,0,0,0,0,0,0};
            #pragma unroll
            for (int d = 0; d < 6; ++d) {
                float x0 = bflo(ha[d]), x1 = bfhi(ha[d]);
                float y0 = bflo(hb[d]), y1 = bfhi(hb[d]);
                #pragma unroll
                for (int j = 0; j < 8; ++j) {
                    uint w = wiL[j*6+d];
                    float wl = bflo(w), wh = bfhi(w);
                    za[j] = fmaf(x0, wl, za[j]); za[j] = fmaf(x1, wh, za[j]);
                    zb[j] = fmaf(y0, wl, zb[j]); zb[j] = fmaf(y1, wh, zb[j]);
                }
            }
            #pragma unroll
            for (int d2 = 1; d2 < 64; d2 <<= 1) {
                #pragma unroll
                for (int j = 0; j < 8; ++j) {
                    za[j] += __shfl_xor(za[j], d2, 64);
                    zb[j] += __shfl_xor(zb[j], d2, 64);
                }
            }
            // ---- circuit for both samples (qc broadcast inline) ----
            float m0[8], m1[8];
            {
                float sc0[8], cc0[8], sc1[8], cc1[8];
                #pragma unroll
                for (int j = 0; j < 8; ++j) {
                    float t0 = tanh_fast(za[j] + bin0[j]);
                    sc0[j] = __sinf(PI_F * t0); cc0[j] = __cosf(PI_F * t0);
                    float t1 = tanh_fast(zb[j] + bin0[j]);
                    sc1[j] = __sinf(PI_F * t1); cc1[j] = __cosf(PI_F * t1);
                }
                float PA0=1.f, PB0=1.f, F0r=1.f, F0i=0.f;
                float PA1=1.f, PB1=1.f, F1r=1.f, F1i=0.f;
                #pragma unroll
                for (int j = 1; j < 8; ++j) {
                    float caj = __shfl(ca_, j, 64), daj = __shfl(da_, j, 64);
                    float krj = __shfl(kr_, j, 64), kij = __shfl(ki_, j, 64);
                    { float u = daj*cc0[j], v = fmaf(krj, sc0[j], caj);
                      m0[j] = fmaf(cc0[0], u, v);
                      PA0 *= (v+u); PB0 *= (v-u);
                      float fi = cc0[j]*kij;
                      float nr = F0r*krj - F0i*fi; F0i = F0r*fi + F0i*krj; F0r = nr; }
                    { float u = daj*cc1[j], v = fmaf(krj, sc1[j], caj);
                      m1[j] = fmaf(cc1[0], u, v);
                      PA1 *= (v+u); PB1 *= (v-u);
                      float fi = cc1[j]*kij;
                      float nr = F1r*krj - F1i*fi; F1i = F1r*fi + F1i*krj; F1r = nr; }
                }
                float ca0 = __shfl(ca_, 0, 64), da0 = __shfl(da_, 0, 64);
                float kr0 = __shfl(kr_, 0, 64), ki0 = __shfl(ki_, 0, 64);
                float DA0 = ca0 + da0, DB0 = ca0 - da0;
                m0[0] = 0.5f*(1.f+cc0[0])*DA0*PA0 + 0.5f*(1.f-cc0[0])*DB0*PB0
                      + sc0[0]*(kr0*F0r - ki0*F0i);
                m1[0] = 0.5f*(1.f+cc1[0])*DA0*PA1 + 0.5f*(1.f-cc1[0])*DB0*PB1
                      + sc1[0]*(kr0*F1r - ki0*F1i);
            }
            // ---- phase C: per-lane 12 output columns, both samples ----
            float ya[12], yb[12];
            float s1a=0.f, s2a=0.f, s1b=0.f, s2b=0.f;
            #pragma unroll
            for (int i = 0; i < 12; ++i) {
                uint4 w = *(const uint4*)(WOd + (size_t)(lane*12 + i)*4);
                float w0=bflo(w.x), w1=bfhi(w.x), w2=bflo(w.y), w3=bfhi(w.y);
                float w4=bflo(w.z), w5=bfhi(w.z), w6=bflo(w.w), w7=bfhi(w.w);
                float bo = (i & 1) ? bfhi(bod[i>>1]) : bflo(bod[i>>1]);
                float a = bo, b = bo;
                a=fmaf(m0[0],w0,a); a=fmaf(m0[1],w1,a); a=fmaf(m0[2],w2,a); a=fmaf(m0[3],w3,a);
                a=fmaf(m0[4],w4,a); a=fmaf(m0[5],w5,a); a=fmaf(m0[6],w6,a); a=fmaf(m0[7],w7,a);
                b=fmaf(m1[0],w0,b); b=fmaf(m1[1],w1,b); b=fmaf(m1[2],w2,b); b=fmaf(m1[3],w3,b);
                b=fmaf(m1[4],w4,b); b=fmaf(m1[5],w5,b); b=fmaf(m1[6],w6,b); b=fmaf(m1[7],w7,b);
                ya[i]=a; s1a+=a; s2a=fmaf(a,a,s2a);
                yb[i]=b; s1b+=b; s2b=fmaf(b,b,s2b);
            }
            #pragma unroll
            for (int d2 = 1; d2 < 64; d2 <<= 1) {
                s1a += __shfl_xor(s1a, d2, 64); s2a += __shfl_xor(s2a, d2, 64);
                s1b += __shfl_xor(s1b, d2, 64); s2b += __shfl_xor(s2b, d2, 64);
            }
            float mua = s1a*(1.f/HID), rsa = rsqrtf(s2a*(1.f/HID) - mua*mua + 1e-5f);
            float mub = s1b*(1.f/HID), rsb = rsqrtf(s2b*(1.f/HID) - mub*mub + 1e-5f);
            uint oa[6], ob[6];
            #pragma unroll
            for (int d = 0; d < 6; ++d) {
                float g0 = bflo(gad[d]), g1 = bfhi(gad[d]);
                float e0_ = bflo(bed[d]), e1_ = bfhi(bed[d]);
                float va0 = (ya[2*d]   - mua)*rsa*g0 + e0_;
                float va1 = (ya[2*d+1] - mua)*rsa*g1 + e1_;
                oa[d] = f2bf(va0) | (f2bf(va1) << 16);
                float vb0 = (yb[2*d]   - mub)*rsb*g0 + e0_;
                float vb1 = (yb[2*d+1] - mub)*rsb*g1 + e1_;
                ob[d] = f2bf(vb0) | (f2bf(vb1) << 16);
            }
            uint* o0 = Od + r0*384 + lane*6;
            *(uint2*)(o0)   = make_uint2(oa[0], oa[1]);
            *(uint2*)(o0+2) = make_uint2(oa[2], oa[3]);
            *(uint2*)(o0+4) = make_uint2(oa[4], oa[5]);
            uint* o1 = o0 + 384;
            *(uint2*)(o1)   = make_uint2(ob[0], ob[1]);
            *(uint2*)(o1+2) = make_uint2(ob[2], ob[3]);
            *(uint2*)(o1+4) = make_uint2(ob[4], ob[5]);
        }
    } else {
        // ================= fp32 fallback (correctness only) =================
        int s = blockIdx.x * 64 + lane;
        if (s >= BATCH) return;
        const float* H  = (const float*)H_;
        const float* WI = (const float*)WI_;
        const float* WO = (const float*)WO_;
        const float* BI = (const float*)bin_;
        const float* BO = (const float*)bout_;
        const float* WRY = (const float*)wry_;
        const float* WRZ = (const float*)wrz_;
        const float* GA = (const float*)gam_;
        const float* BE = (const float*)bet_;
        float* O = (float*)out_;
        float qc[32];
        for (int q = 0; q < 8; ++q) {
            float ry0 = WRY[q], ry1 = WRY[8+q], rz0 = WRZ[q], rz1 = WRZ[8+q];
            float cA = cosf(0.5f*ry0), sA = sinf(0.5f*ry0);
            float cB = cosf(0.5f*ry1), sB = sinf(0.5f*ry1);
            float p0c = cosf(0.5f*rz0), p0s = sinf(0.5f*rz0);
            float p1c = cosf(0.5f*rz1), p1s = sinf(0.5f*rz1);
            float g00r =  cA*p0c, g00i = -cA*p0s;
            float g01r = -sA*p0c, g01i =  sA*p0s;
            float g10r =  sA*p0c, g10i =  sA*p0s;
            float g11r =  cA*p0c, g11i =  cA*p0s;
            float h00r = cB*g00r - sB*g10r, h00i = cB*g00i - sB*g10i;
            float h01r = cB*g01r - sB*g11r, h01i = cB*g01i - sB*g11i;
            float h10r = sB*g00r + cB*g10r, h10i = sB*g00i + cB*g10i;
            float h11r = sB*g01r + cB*g11r, h11i = sB*g01i + cB*g11i;
            float f00r = h00r*p1c + h00i*p1s, f00i = h00i*p1c - h00r*p1s;
            float f01r = h01r*p1c + h01i*p1s, f01i = h01i*p1c - h01r*p1s;
            float f10r = h10r*p1c - h10i*p1s, f10i = h10i*p1c + h10r*p1s;
            float f11r = h11r*p1c - h11i*p1s, f11i = h11i*p1c + h11r*p1s;
            qc[q*4+0] = f00r*f00r + f00i*f00i - (f10r*f10r + f10i*f10i);
            qc[q*4+1] = f01r*f01r + f01i*f01i - (f11r*f11r + f11i*f11i);
            qc[q*4+2] = (f00r*f01r + f00i*f01i) - (f10r*f11r + f10i*f11i);
            qc[q*4+3] = (f00i*f01r - f00r*f01i) - (f10i*f11r - f10r*f11i);
        }
        float z[8];
        #pragma unroll
        for (int j = 0; j < 8; ++j) z[j] = BI[j];
        for (int c = 0; c < HID; ++c) {
            float h = H[(size_t)s*HID + c];
            #pragma unroll
            for (int j = 0; j < 8; ++j) z[j] = fmaf(h, WI[j*HID + c], z[j]);
        }
        float meas[8];
        circuit_qc(z, qc, meas);
        float s1 = 0.f, s2 = 0.f;
        for (int h = 0; h < HID; ++h) {
            float v = BO[h];
            #pragma unroll
            for (int j = 0; j < 8; ++j) v = fmaf(meas[j], WO[h*8 + j], v);
            s1 += v; s2 = fmaf(v, v, s2);
        }
        float mu = s1*(1.f/HID);
        float rs = rsqrtf(s2*(1.f/HID) - mu*mu + 1e-5f);
        for (int h = 0; h < HID; ++h) {
            float v = BO[h];
            #pragma unroll
            for (int j = 0; j < 8; ++j) v = fmaf(meas[j], WO[h*8 + j], v);
            O[(size_t)s*HID + h] = (v - mu)*rs*GA[h] + BE[h];
        }
    }
}

extern "C" void kernel_launch(void* const* d_in, const int* in_sizes, int n_in,
                              void* d_out, int out_size, void* d_ws, size_t ws_size,
                              hipStream_t stream) {
    fused_kernel<<<NBLK, 64, 0, stream>>>(
        d_in[0], d_in[1], d_in[2], d_in[3], d_in[4],
        d_in[5], d_in[6], d_in[7], d_in[8], d_out);
}